// Round 1
// baseline (106.607 us; speedup 1.0000x reference)
//
#include <hip/hip_runtime.h>

typedef __attribute__((ext_vector_type(4))) float f32x4;
typedef __attribute__((ext_vector_type(8))) __bf16 bf16x8;
typedef __attribute__((ext_vector_type(8))) unsigned short ushort8;

static __device__ __forceinline__ unsigned short f2bf(float f) {
  unsigned u = __float_as_uint(f);
  u += 0x7fffu + ((u >> 16) & 1u);   // RNE
  return (unsigned short)(u >> 16);
}

// ---------------------------------------------------------------------------
// Kernel 1 (fused): xT[b][p][ci] = bf16(x[b][ci][p]);  wpk[tap][co][ci] = bf16(conv_w[co][ci][tap])
// ---------------------------------------------------------------------------
__global__ __launch_bounds__(256, 1) void k_convert(
    const float* __restrict__ x, const float* __restrict__ cw,
    unsigned short* __restrict__ xT, unsigned short* __restrict__ wpk) {
  int bid = blockIdx.x;
  if (bid < 1568) {                       // 1568*256 = 401408 = 8*784*64
    int idx  = bid * 256 + threadIdx.x;
    int cig  = (idx & 63) * 8;            // ci base (8 per thread)
    int rest = idx >> 6;                  // b*784 + p
    int p = rest % 784, b = rest / 784;
    const float* src = x + ((size_t)(b * 512 + cig)) * 784 + p;
    ushort8 o;
#pragma unroll
    for (int j = 0; j < 8; ++j) o[j] = f2bf(src[(size_t)j * 784]);
    *reinterpret_cast<ushort8*>(xT + ((size_t)(b * 784 + p)) * 512 + cig) = o;
  } else {                                // 1152 blocks -> 294912 = 9*64*512
    int idx = (bid - 1568) * 256 + threadIdx.x;
    if (idx < 294912) {
      int ci = idx & 511, rest = idx >> 9;
      int co = rest & 63, tap = rest >> 6;
      wpk[idx] = f2bf(cw[((size_t)(co * 512 + ci)) * 9 + tap]);
    }
  }
}

// ---------------------------------------------------------------------------
// Kernel 2: conv3x3 via bf16 MFMA, tap-decomposed implicit GEMM.
// grid 224 = 8b * 7px * 2co2 * 2split ; block 128 (2 waves)
// writes am_part[s][b][p][co]  (p-major, co contiguous -> float4 stores)
// ---------------------------------------------------------------------------
#define CPAD 56
__global__ __launch_bounds__(128, 1) void k_conv(
    const unsigned short* __restrict__ xT, const unsigned short* __restrict__ wpk,
    float* __restrict__ am_part) {
  __shared__ unsigned short wl[9 * 32 * CPAD];  // [tap][co_l 32][ci 32 pad 56]
  __shared__ unsigned short xl[168 * CPAD];     // [pos 6rows*28][ci 32 pad 56]
  int bid = blockIdx.x;
  int s  = bid & 1;
  int c2 = (bid >> 1) & 1;
  int px = (bid >> 2) % 7;
  int b  = bid / 28;
  int t = threadIdx.x;
  int W = t >> 6, lane = t & 63;
  int co_base = c2 * 32;
  int p0 = px * 112, h0 = px * 4;
  int n = lane & 15, kg = lane >> 4;

  int lrow0[7], wc[7];
#pragma unroll
  for (int f = 0; f < 7; ++f) {
    int pit = f * 16 + n;
    lrow0[f] = pit / 28 + 1;
    wc[f]    = pit % 28;
  }
  f32x4 acc[7];
#pragma unroll
  for (int f = 0; f < 7; ++f) acc[f] = {0.f, 0.f, 0.f, 0.f};
  const ushort8 bzero = {0, 0, 0, 0, 0, 0, 0, 0};

  for (int c = 0; c < 8; ++c) {           // 8 ci-chunks of 32 (split covers 256 ci)
    int ci_c = s * 256 + c * 32;
    __syncthreads();
    // stage weights: 9*32*32 bf16 = 1152 x b128 / 128 thr = 9 each
#pragma unroll
    for (int i = 0; i < 9; ++i) {
      int q = i * 128 + t;
      int tapco = q >> 2, ci8 = (q & 3) * 8;
      int tap = tapco >> 5, co_l = tapco & 31;
      ushort8 v = *reinterpret_cast<const ushort8*>(
          wpk + ((size_t)(tap * 64 + co_base + co_l)) * 512 + ci_c + ci8);
      *reinterpret_cast<ushort8*>(&wl[(tap * 32 + co_l) * CPAD + ci8]) = v;
    }
    // stage x halo tile: 168 pos * 32 ci = 672 x b128
#pragma unroll
    for (int i = 0; i < 6; ++i) {
      int q = i * 128 + t;
      if (q < 672) {
        int pos = q >> 2, ci8 = (q & 3) * 8;
        int lr = pos / 28, c_ = pos % 28;
        int h = h0 - 1 + lr;
        ushort8 v = bzero;
        if (h >= 0 && h < 28)
          v = *reinterpret_cast<const ushort8*>(
              xT + ((size_t)(b * 784 + h * 28 + c_)) * 512 + ci_c + ci8);
        *reinterpret_cast<ushort8*>(&xl[pos * CPAD + ci8]) = v;
      }
    }
    __syncthreads();
#pragma unroll
    for (int tap = 0; tap < 9; ++tap) {
      int dh = tap / 3 - 1, dw = tap % 3 - 1;
      bf16x8 a = *reinterpret_cast<const bf16x8*>(
          &wl[(tap * 32 + W * 16 + n) * CPAD + kg * 8]);
#pragma unroll
      for (int f = 0; f < 7; ++f) {
        int wcd = wc[f] + dw;
        bool valid = (unsigned)wcd < 28u;
        int pos = (lrow0[f] + dh) * 28 + wcd;
        int posc = valid ? pos : 0;
        ushort8 bv = *reinterpret_cast<const ushort8*>(&xl[posc * CPAD + kg * 8]);
        if (!valid) bv = bzero;
        acc[f] = __builtin_amdgcn_mfma_f32_16x16x32_bf16(
            a, __builtin_bit_cast(bf16x8, bv), acc[f], 0, 0, 0);
      }
    }
  }
  // D: col = lane&15 (pixel), row = kg*4 + reg (co) -> float4 store over co
#pragma unroll
  for (int f = 0; f < 7; ++f) {
    int p  = p0 + f * 16 + n;
    int co = co_base + W * 16 + kg * 4;
    *reinterpret_cast<f32x4*>(am_part + ((size_t)((s * 8 + b) * 784 + p)) * 64 + co) = acc[f];
  }
}

// ---------------------------------------------------------------------------
// Kernel 3: am assemble (sum splits + bias) + outer-product partial max-pool
// grid 448 = 8b * 8cit * 7pc ; block 256 ; pmax[pc][b][ci][co]
// ---------------------------------------------------------------------------
__global__ __launch_bounds__(256, 1) void k_pool(
    const float* __restrict__ x, const float* __restrict__ am_part,
    const float* __restrict__ conv_b, float* __restrict__ pmax) {
  __shared__ float aml[112 * 64];    // [p][co]
  __shared__ float xls[64 * 116];    // [ci][p pad116]
  int bid = blockIdx.x;
  int pc  = bid % 7;
  int cit = (bid / 7) & 7;
  int b   = bid / 56;
  int t = threadIdx.x;
  int p0 = pc * 112;
#pragma unroll
  for (int i = 0; i < 7; ++i) {      // 1792 float4 of am
    int idx = i * 256 + t;
    int p = idx >> 4, cog = (idx & 15) * 4;
    size_t o0 = ((size_t)(b * 784 + p0 + p)) * 64 + cog;
    f32x4 v = *reinterpret_cast<const f32x4*>(am_part + o0);
    f32x4 v2 = *reinterpret_cast<const f32x4*>(am_part + o0 + (size_t)8 * 784 * 64);
    f32x4 bb = *reinterpret_cast<const f32x4*>(conv_b + cog);
    v = v + v2 + bb;
    *reinterpret_cast<f32x4*>(&aml[p * 64 + cog]) = v;
  }
#pragma unroll
  for (int i = 0; i < 7; ++i) {      // 1792 float4 of x (fp32, exact)
    int idx = i * 256 + t;
    int ci = idx / 28, p4 = (idx % 28) * 4;
    f32x4 v = *reinterpret_cast<const f32x4*>(
        x + ((size_t)(b * 512 + cit * 64 + ci)) * 784 + p0 + p4);
    *reinterpret_cast<f32x4*>(&xls[ci * 116 + p4]) = v;
  }
  __syncthreads();
  int co4 = (t & 15) * 4, ci4 = (t >> 4) * 4;
  float m[4][4];
#pragma unroll
  for (int i = 0; i < 4; ++i)
#pragma unroll
    for (int j = 0; j < 4; ++j) m[i][j] = -3.4e38f;
  for (int p = 0; p < 112; ++p) {
    f32x4 a4 = *reinterpret_cast<const f32x4*>(&aml[p * 64 + co4]);
    float xv[4];
#pragma unroll
    for (int i = 0; i < 4; ++i) xv[i] = xls[(ci4 + i) * 116 + p];
#pragma unroll
    for (int i = 0; i < 4; ++i)
#pragma unroll
      for (int j = 0; j < 4; ++j) m[i][j] = fmaxf(m[i][j], xv[i] * a4[j]);
  }
#pragma unroll
  for (int i = 0; i < 4; ++i) {
    f32x4 v = {m[i][0], m[i][1], m[i][2], m[i][3]};
    *reinterpret_cast<f32x4*>(
        pmax + ((size_t)((pc * 8 + b) * 512 + cit * 64 + ci4 + i)) * 64 + co4) = v;
  }
}

// ---------------------------------------------------------------------------
// Kernel 4: combine 7 pixel-chunk partial maxes -> x_pool output
// ---------------------------------------------------------------------------
__global__ __launch_bounds__(256, 1) void k_combine(
    const float* __restrict__ pmax, float* __restrict__ xpool) {
  size_t idx = ((size_t)blockIdx.x * 256 + threadIdx.x) * 4;   // 262144 floats
  f32x4 v = *reinterpret_cast<const f32x4*>(pmax + idx);
#pragma unroll
  for (int pc = 1; pc < 7; ++pc) {
    f32x4 u = *reinterpret_cast<const f32x4*>(pmax + (size_t)pc * 262144 + idx);
#pragma unroll
    for (int j = 0; j < 4; ++j) v[j] = fmaxf(v[j], u[j]);
  }
  *reinterpret_cast<f32x4*>(xpool + idx) = v;
}

// ---------------------------------------------------------------------------
// Kernel 5: fc6 split-K GEMV-8. grid 512 = 4kc * 128rg ; 8 rows x 8 batches/thread
// ---------------------------------------------------------------------------
__global__ __launch_bounds__(256, 1) void k_fc6(
    const float* __restrict__ flat, const float* __restrict__ w6,
    float* __restrict__ part6) {
  __shared__ float red[4][8][66];
  int bid = blockIdx.x;
  int kc = bid & 3, rg = bid >> 2;
  int t = threadIdx.x, W = t >> 6, lane = t & 63;
  int r0 = rg * 8;
  float acc[8][8];
#pragma unroll
  for (int r = 0; r < 8; ++r)
#pragma unroll
    for (int b = 0; b < 8; ++b) acc[r][b] = 0.f;
  int kbase = kc * 8192 + t * 4;
  for (int step = 0; step < 8; ++step) {
    int k = kbase + step * 1024;
    f32x4 f4[8], w4[8];
#pragma unroll
    for (int b = 0; b < 8; ++b)
      f4[b] = *reinterpret_cast<const f32x4*>(flat + (size_t)b * 32768 + k);
#pragma unroll
    for (int r = 0; r < 8; ++r)
      w4[r] = *reinterpret_cast<const f32x4*>(w6 + (size_t)(r0 + r) * 32768 + k);
#pragma unroll
    for (int r = 0; r < 8; ++r)
#pragma unroll
      for (int b = 0; b < 8; ++b)
        acc[r][b] += w4[r][0] * f4[b][0] + w4[r][1] * f4[b][1] +
                     w4[r][2] * f4[b][2] + w4[r][3] * f4[b][3];
  }
#pragma unroll
  for (int r = 0; r < 8; ++r)
#pragma unroll
    for (int b = 0; b < 8; ++b) {
      float v = acc[r][b];
      v += __shfl_down(v, 32, 64);
      v += __shfl_down(v, 16, 64);
      v += __shfl_down(v, 8, 64);
      acc[r][b] = v;
    }
  if (lane < 8) {
#pragma unroll
    for (int r = 0; r < 8; ++r)
#pragma unroll
      for (int b = 0; b < 8; ++b) red[W][lane][r * 8 + b] = acc[r][b];
  }
  __syncthreads();
  if (t < 64) {
    float sum = 0.f;
#pragma unroll
    for (int w = 0; w < 4; ++w)
#pragma unroll
      for (int l = 0; l < 8; ++l) sum += red[w][l][t];
    int r = t >> 3, b = t & 7;
    part6[(size_t)kc * 8192 + (r0 + r) * 8 + b] = sum;
  }
}

// ---------------------------------------------------------------------------
// Kernel 6: reduce fc6 partials + bias + relu -> h[b][r]
// ---------------------------------------------------------------------------
__global__ __launch_bounds__(256, 1) void k_h(
    const float* __restrict__ part6, const float* __restrict__ b6,
    float* __restrict__ h) {
  int idx = blockIdx.x * 256 + threadIdx.x;   // 8192
  int r = idx >> 3, b = idx & 7;
  float s = b6[r];
#pragma unroll
  for (int kc = 0; kc < 4; ++kc) s += part6[(size_t)kc * 8192 + r * 8 + b];
  h[b * 1024 + r] = fmaxf(s, 0.f);
}

// ---------------------------------------------------------------------------
// Kernel 7: fc7 wave-per-row + bias + relu -> out[b][r]
// ---------------------------------------------------------------------------
__global__ __launch_bounds__(256, 1) void k_fc7(
    const float* __restrict__ h, const float* __restrict__ w7,
    const float* __restrict__ b7, float* __restrict__ out) {
  int bid = blockIdx.x;                        // 256
  int t = threadIdx.x, W = t >> 6, lane = t & 63;
  int r = bid * 4 + W;
  float acc[8] = {0, 0, 0, 0, 0, 0, 0, 0};
#pragma unroll
  for (int step = 0; step < 4; ++step) {
    int k = step * 256 + lane * 4;
    f32x4 w4 = *reinterpret_cast<const f32x4*>(w7 + (size_t)r * 1024 + k);
#pragma unroll
    for (int b = 0; b < 8; ++b) {
      f32x4 h4 = *reinterpret_cast<const f32x4*>(h + b * 1024 + k);
      acc[b] += w4[0] * h4[0] + w4[1] * h4[1] + w4[2] * h4[2] + w4[3] * h4[3];
    }
  }
#pragma unroll
  for (int b = 0; b < 8; ++b) {
    float v = acc[b];
#pragma unroll
    for (int off = 32; off > 0; off >>= 1) v += __shfl_down(v, off, 64);
    acc[b] = v;
  }
  if (lane == 0) {
#pragma unroll
    for (int b = 0; b < 8; ++b) out[b * 1024 + r] = fmaxf(acc[b] + b7[r], 0.f);
  }
}

// ---------------------------------------------------------------------------
extern "C" void kernel_launch(void* const* d_in, const int* in_sizes, int n_in,
                              void* d_out, int out_size, void* d_ws, size_t ws_size,
                              hipStream_t stream) {
  const float* x  = (const float*)d_in[0];
  const float* cw = (const float*)d_in[1];
  const float* cb = (const float*)d_in[2];
  const float* w6 = (const float*)d_in[3];
  const float* b6 = (const float*)d_in[4];
  const float* w7 = (const float*)d_in[5];
  const float* b7 = (const float*)d_in[6];
  float* out   = (float*)d_out;            // (8,1024) = 8192
  float* xpool = out + 8192;               // (8,512,64) = 262144

  char* ws = (char*)d_ws;
  unsigned short* xT  = (unsigned short*)(ws);                 // 6,422,528 B
  unsigned short* wpk = (unsigned short*)(ws + 6422528);       //   589,824 B
  float* am_part      = (float*)(ws + 7012352);                // 3,211,264 B
  float* pmax         = (float*)(ws + 10223616);               // 7,340,032 B
  float* part6        = (float*)(ws + 17563648);               //   131,072 B
  float* hbuf         = (float*)(ws + 17694720);               //    32,768 B

  hipLaunchKernelGGL(k_convert, dim3(2720), dim3(256), 0, stream, x, cw, xT, wpk);
  hipLaunchKernelGGL(k_conv,    dim3(224),  dim3(128), 0, stream, xT, wpk, am_part);
  hipLaunchKernelGGL(k_pool,    dim3(448),  dim3(256), 0, stream, x, am_part, cb, pmax);
  hipLaunchKernelGGL(k_combine, dim3(256),  dim3(256), 0, stream, pmax, xpool);
  hipLaunchKernelGGL(k_fc6,     dim3(512),  dim3(256), 0, stream, xpool, w6, part6);
  hipLaunchKernelGGL(k_h,       dim3(32),   dim3(256), 0, stream, part6, b6, hbuf);
  hipLaunchKernelGGL(k_fc7,     dim3(256),  dim3(256), 0, stream, hbuf, w7, b7, out);
}

// Round 2
// 96.188 us; speedup vs baseline: 1.1083x; 1.1083x over previous
//
#include <hip/hip_runtime.h>

typedef __attribute__((ext_vector_type(4))) float f32x4;
typedef __attribute__((ext_vector_type(8))) __bf16 bf16x8;
typedef __attribute__((ext_vector_type(8))) unsigned short ushort8;

static __device__ __forceinline__ unsigned short f2bf(float f) {
  unsigned u = __float_as_uint(f);
  u += 0x7fffu + ((u >> 16) & 1u);   // RNE
  return (unsigned short)(u >> 16);
}

// ---------------------------------------------------------------------------
// Kernel 1: LDS-tiled transpose x[b][ci][p] (f32) -> xT[b][p][ci] (bf16),
// plus weight repack conv_w[co][ci][3][3] -> wpk[tap][co][ci] (bf16).
// grid 968 = 896 transpose tiles (8b * 8cit * 14pt) + 72 weight blocks
// ---------------------------------------------------------------------------
__global__ __launch_bounds__(256, 1) void k_xpose(
    const float* __restrict__ x, const float* __restrict__ cw,
    unsigned short* __restrict__ xT, unsigned short* __restrict__ wpk) {
  int bid = blockIdx.x;
  int t = threadIdx.x;
  if (bid < 896) {
    __shared__ float xl[64 * 57];            // [ci 64][p 56 pad 57]
    int pt = bid % 14, cit = (bid / 14) & 7, b = bid / 112;
    int p0 = pt * 56, ci0 = cit * 64;
#pragma unroll
    for (int i = 0; i < 4; ++i) {            // 896 f32x4 coalesced reads
      int idx = i * 256 + t;
      if (idx < 896) {
        int ci = idx / 14, p4 = (idx % 14) * 4;
        f32x4 v = *reinterpret_cast<const f32x4*>(
            x + ((size_t)(b * 512 + ci0 + ci)) * 784 + p0 + p4);
        *reinterpret_cast<f32x4*>(&xl[ci * 57 + p4]) = v;
      }
    }
    __syncthreads();
#pragma unroll
    for (int i = 0; i < 2; ++i) {            // 448 ushort8 coalesced writes
      int idx = i * 256 + t;
      if (idx < 448) {
        int p = idx >> 3, c8 = (idx & 7) * 8;
        ushort8 o;
#pragma unroll
        for (int j = 0; j < 8; ++j) o[j] = f2bf(xl[(c8 + j) * 57 + p]);
        *reinterpret_cast<ushort8*>(
            xT + ((size_t)(b * 784 + p0 + p)) * 512 + ci0 + c8) = o;
      }
    }
  } else {                                   // 72 blocks * 4096 = 294912 wpk elems
    int o0 = (bid - 896) * 4096 + t * 16;
    ushort8 w0, w1;
#pragma unroll
    for (int j = 0; j < 16; ++j) {
      int o = o0 + j;
      int ci = o & 511, co = (o >> 9) & 63, tap = o >> 15;
      unsigned short v = f2bf(cw[((size_t)(co * 512 + ci)) * 9 + tap]);
      if (j < 8) w0[j] = v; else w1[j - 8] = v;
    }
    *reinterpret_cast<ushort8*>(wpk + o0) = w0;
    *reinterpret_cast<ushort8*>(wpk + o0 + 8) = w1;
  }
}

// ---------------------------------------------------------------------------
// Kernel 2: conv3x3 via bf16 MFMA, tap-decomposed implicit GEMM.
// grid 448 = 8b * 7px * 2co2 * 4split ; block 128 (2 waves)
// bias folded into the s==0 accumulator init.
// writes am_part[s][b][p][co]
// ---------------------------------------------------------------------------
#define CPAD 56
__global__ __launch_bounds__(128, 1) void k_conv(
    const unsigned short* __restrict__ xT, const unsigned short* __restrict__ wpk,
    const float* __restrict__ cb, float* __restrict__ am_part) {
  __shared__ unsigned short wl[9 * 32 * CPAD];  // [tap][co_l 32][ci 32 pad 56]
  __shared__ unsigned short xl[168 * CPAD];     // [pos 6rows*28][ci 32 pad 56]
  int bid = blockIdx.x;
  int s  = bid & 3;
  int c2 = (bid >> 2) & 1;
  int px = (bid >> 3) % 7;
  int b  = bid / 56;
  int t = threadIdx.x;
  int W = t >> 6, lane = t & 63;
  int co_base = c2 * 32;
  int p0 = px * 112, h0 = px * 4;
  int n = lane & 15, kg = lane >> 4;

  int lrow0[7], wc[7];
#pragma unroll
  for (int f = 0; f < 7; ++f) {
    int pit = f * 16 + n;
    lrow0[f] = pit / 28 + 1;
    wc[f]    = pit % 28;
  }
  f32x4 acc[7];
  f32x4 cb4 = {0.f, 0.f, 0.f, 0.f};
  if (s == 0)
    cb4 = *reinterpret_cast<const f32x4*>(cb + co_base + W * 16 + kg * 4);
#pragma unroll
  for (int f = 0; f < 7; ++f) acc[f] = cb4;
  const ushort8 bzero = {0, 0, 0, 0, 0, 0, 0, 0};

  for (int c = 0; c < 4; ++c) {           // 4 ci-chunks of 32 (split covers 128 ci)
    int ci_c = s * 128 + c * 32;
    __syncthreads();
    // stage weights: 9*32*32 bf16 = 1152 x b128 / 128 thr = 9 each
#pragma unroll
    for (int i = 0; i < 9; ++i) {
      int q = i * 128 + t;
      int tapco = q >> 2, ci8 = (q & 3) * 8;
      int tap = tapco >> 5, co_l = tapco & 31;
      ushort8 v = *reinterpret_cast<const ushort8*>(
          wpk + ((size_t)(tap * 64 + co_base + co_l)) * 512 + ci_c + ci8);
      *reinterpret_cast<ushort8*>(&wl[(tap * 32 + co_l) * CPAD + ci8]) = v;
    }
    // stage x halo tile: 168 pos * 32 ci = 672 x b128
#pragma unroll
    for (int i = 0; i < 6; ++i) {
      int q = i * 128 + t;
      if (q < 672) {
        int pos = q >> 2, ci8 = (q & 3) * 8;
        int lr = pos / 28, c_ = pos % 28;
        int h = h0 - 1 + lr;
        ushort8 v = bzero;
        if (h >= 0 && h < 28)
          v = *reinterpret_cast<const ushort8*>(
              xT + ((size_t)(b * 784 + h * 28 + c_)) * 512 + ci_c + ci8);
        *reinterpret_cast<ushort8*>(&xl[pos * CPAD + ci8]) = v;
      }
    }
    __syncthreads();
#pragma unroll
    for (int tap = 0; tap < 9; ++tap) {
      int dh = tap / 3 - 1, dw = tap % 3 - 1;
      bf16x8 a = *reinterpret_cast<const bf16x8*>(
          &wl[(tap * 32 + W * 16 + n) * CPAD + kg * 8]);
#pragma unroll
      for (int f = 0; f < 7; ++f) {
        int wcd = wc[f] + dw;
        bool valid = (unsigned)wcd < 28u;
        int pos = (lrow0[f] + dh) * 28 + wcd;
        int posc = valid ? pos : 0;
        ushort8 bv = *reinterpret_cast<const ushort8*>(&xl[posc * CPAD + kg * 8]);
        if (!valid) bv = bzero;
        acc[f] = __builtin_amdgcn_mfma_f32_16x16x32_bf16(
            a, __builtin_bit_cast(bf16x8, bv), acc[f], 0, 0, 0);
      }
    }
  }
  // D: col = lane&15 (pixel), row = kg*4 + reg (co) -> float4 store over co
#pragma unroll
  for (int f = 0; f < 7; ++f) {
    int p  = p0 + f * 16 + n;
    int co = co_base + W * 16 + kg * 4;
    *reinterpret_cast<f32x4*>(
        am_part + ((size_t)((s * 8 + b) * 784 + p)) * 64 + co) = acc[f];
  }
}

// ---------------------------------------------------------------------------
// Kernel 3: am assemble (sum 4 splits) + outer-product partial max-pool
// grid 448 = 8b * 8cit * 7pc ; block 256 ; pmax[pc][b][ci][co]
// x staged in LDS as [p][ci] so inner loop is 2x ds_read_b128 + pure VALU.
// ---------------------------------------------------------------------------
__global__ __launch_bounds__(256, 1) void k_pool(
    const float* __restrict__ x, const float* __restrict__ am_part,
    float* __restrict__ pmax) {
  __shared__ float aml[112 * 64];    // [p][co]           28 KB
  __shared__ float xls[112 * 65];    // [p][ci pad 65]    29 KB
  int bid = blockIdx.x;
  int pc  = bid % 7;
  int cit = (bid / 7) & 7;
  int b   = bid / 56;
  int t = threadIdx.x;
  int p0 = pc * 112;
#pragma unroll
  for (int i = 0; i < 7; ++i) {      // 1792 float4 of am (sum 4 splits)
    int idx = i * 256 + t;
    int p = idx >> 4, cog = (idx & 15) * 4;
    size_t o0 = ((size_t)(b * 784 + p0 + p)) * 64 + cog;
    f32x4 v = *reinterpret_cast<const f32x4*>(am_part + o0);
#pragma unroll
    for (int s2 = 1; s2 < 4; ++s2)
      v = v + *reinterpret_cast<const f32x4*>(am_part + o0 + (size_t)s2 * 8 * 784 * 64);
    *reinterpret_cast<f32x4*>(&aml[p * 64 + cog]) = v;
  }
#pragma unroll
  for (int i = 0; i < 7; ++i) {      // 1792 float4 of x, transposed into [p][ci]
    int idx = i * 256 + t;
    int ci = idx / 28, p4 = (idx % 28) * 4;
    f32x4 v = *reinterpret_cast<const f32x4*>(
        x + ((size_t)(b * 512 + cit * 64 + ci)) * 784 + p0 + p4);
#pragma unroll
    for (int q = 0; q < 4; ++q) xls[(p4 + q) * 65 + ci] = v[q];
  }
  __syncthreads();
  int co4 = (t & 15) * 4, ci4 = (t >> 4) * 4;
  float m[4][4];
#pragma unroll
  for (int i = 0; i < 4; ++i)
#pragma unroll
    for (int j = 0; j < 4; ++j) m[i][j] = -3.4e38f;
  for (int p = 0; p < 112; ++p) {
    f32x4 a4 = *reinterpret_cast<const f32x4*>(&aml[p * 64 + co4]);
    f32x4 xv = *reinterpret_cast<const f32x4*>(&xls[p * 65 + ci4]);
#pragma unroll
    for (int i = 0; i < 4; ++i)
#pragma unroll
      for (int j = 0; j < 4; ++j) m[i][j] = fmaxf(m[i][j], xv[i] * a4[j]);
  }
#pragma unroll
  for (int i = 0; i < 4; ++i) {
    f32x4 v = {m[i][0], m[i][1], m[i][2], m[i][3]};
    *reinterpret_cast<f32x4*>(
        pmax + ((size_t)((pc * 8 + b) * 512 + cit * 64 + ci4 + i)) * 64 + co4) = v;
  }
}

// ---------------------------------------------------------------------------
// Kernel 4: combine 7 pixel-chunk partial maxes -> x_pool output
// ---------------------------------------------------------------------------
__global__ __launch_bounds__(256, 1) void k_combine(
    const float* __restrict__ pmax, float* __restrict__ xpool) {
  size_t idx = ((size_t)blockIdx.x * 256 + threadIdx.x) * 4;   // 262144 floats
  f32x4 v = *reinterpret_cast<const f32x4*>(pmax + idx);
#pragma unroll
  for (int pc = 1; pc < 7; ++pc) {
    f32x4 u = *reinterpret_cast<const f32x4*>(pmax + (size_t)pc * 262144 + idx);
#pragma unroll
    for (int j = 0; j < 4; ++j) v[j] = fmaxf(v[j], u[j]);
  }
  *reinterpret_cast<f32x4*>(xpool + idx) = v;
}

// ---------------------------------------------------------------------------
// Kernel 5: fc6 split-K GEMV-8. grid 1024 = 8kc * 128rg ; 8 rows x 8 batches/thr
// ---------------------------------------------------------------------------
__global__ __launch_bounds__(256, 1) void k_fc6(
    const float* __restrict__ flat, const float* __restrict__ w6,
    float* __restrict__ part6) {
  __shared__ float red[4][8][66];
  int bid = blockIdx.x;
  int kc = bid & 7, rg = bid >> 3;
  int t = threadIdx.x, W = t >> 6, lane = t & 63;
  int r0 = rg * 8;
  float acc[8][8];
#pragma unroll
  for (int r = 0; r < 8; ++r)
#pragma unroll
    for (int b = 0; b < 8; ++b) acc[r][b] = 0.f;
  int kbase = kc * 4096 + t * 4;
#pragma unroll
  for (int step = 0; step < 4; ++step) {
    int k = kbase + step * 1024;
    f32x4 f4[8], w4[8];
#pragma unroll
    for (int b = 0; b < 8; ++b)
      f4[b] = *reinterpret_cast<const f32x4*>(flat + (size_t)b * 32768 + k);
#pragma unroll
    for (int r = 0; r < 8; ++r)
      w4[r] = *reinterpret_cast<const f32x4*>(w6 + (size_t)(r0 + r) * 32768 + k);
#pragma unroll
    for (int r = 0; r < 8; ++r)
#pragma unroll
      for (int b = 0; b < 8; ++b)
        acc[r][b] += w4[r][0] * f4[b][0] + w4[r][1] * f4[b][1] +
                     w4[r][2] * f4[b][2] + w4[r][3] * f4[b][3];
  }
#pragma unroll
  for (int r = 0; r < 8; ++r)
#pragma unroll
    for (int b = 0; b < 8; ++b) {
      float v = acc[r][b];
      v += __shfl_down(v, 32, 64);
      v += __shfl_down(v, 16, 64);
      v += __shfl_down(v, 8, 64);
      acc[r][b] = v;
    }
  if (lane < 8) {
#pragma unroll
    for (int r = 0; r < 8; ++r)
#pragma unroll
      for (int b = 0; b < 8; ++b) red[W][lane][r * 8 + b] = acc[r][b];
  }
  __syncthreads();
  if (t < 64) {
    float sum = 0.f;
#pragma unroll
    for (int w = 0; w < 4; ++w)
#pragma unroll
      for (int l = 0; l < 8; ++l) sum += red[w][l][t];
    int r = t >> 3, b = t & 7;
    part6[(size_t)kc * 8192 + (r0 + r) * 8 + b] = sum;
  }
}

// ---------------------------------------------------------------------------
// Kernel 6: reduce fc6 partials + bias + relu -> h[b][r]
// ---------------------------------------------------------------------------
__global__ __launch_bounds__(256, 1) void k_h(
    const float* __restrict__ part6, const float* __restrict__ b6,
    float* __restrict__ h) {
  int idx = blockIdx.x * 256 + threadIdx.x;   // 8192
  int r = idx >> 3, b = idx & 7;
  float s = b6[r];
#pragma unroll
  for (int kc = 0; kc < 8; ++kc) s += part6[(size_t)kc * 8192 + r * 8 + b];
  h[b * 1024 + r] = fmaxf(s, 0.f);
}

// ---------------------------------------------------------------------------
// Kernel 7: fc7 wave-per-row + bias + relu -> out[b][r]
// ---------------------------------------------------------------------------
__global__ __launch_bounds__(256, 1) void k_fc7(
    const float* __restrict__ h, const float* __restrict__ w7,
    const float* __restrict__ b7, float* __restrict__ out) {
  int bid = blockIdx.x;                        // 256
  int t = threadIdx.x, W = t >> 6, lane = t & 63;
  int r = bid * 4 + W;
  float acc[8] = {0, 0, 0, 0, 0, 0, 0, 0};
#pragma unroll
  for (int step = 0; step < 4; ++step) {
    int k = step * 256 + lane * 4;
    f32x4 w4 = *reinterpret_cast<const f32x4*>(w7 + (size_t)r * 1024 + k);
#pragma unroll
    for (int b = 0; b < 8; ++b) {
      f32x4 h4 = *reinterpret_cast<const f32x4*>(h + b * 1024 + k);
      acc[b] += w4[0] * h4[0] + w4[1] * h4[1] + w4[2] * h4[2] + w4[3] * h4[3];
    }
  }
#pragma unroll
  for (int b = 0; b < 8; ++b) {
    float v = acc[b];
#pragma unroll
    for (int off = 32; off > 0; off >>= 1) v += __shfl_down(v, off, 64);
    acc[b] = v;
  }
  if (lane == 0) {
#pragma unroll
    for (int b = 0; b < 8; ++b) out[b * 1024 + r] = fmaxf(acc[b] + b7[r], 0.f);
  }
}

// ---------------------------------------------------------------------------
extern "C" void kernel_launch(void* const* d_in, const int* in_sizes, int n_in,
                              void* d_out, int out_size, void* d_ws, size_t ws_size,
                              hipStream_t stream) {
  const float* x  = (const float*)d_in[0];
  const float* cw = (const float*)d_in[1];
  const float* cb = (const float*)d_in[2];
  const float* w6 = (const float*)d_in[3];
  const float* b6 = (const float*)d_in[4];
  const float* w7 = (const float*)d_in[5];
  const float* b7 = (const float*)d_in[6];
  float* out   = (float*)d_out;            // (8,1024) = 8192
  float* xpool = out + 8192;               // (8,512,64) = 262144

  char* ws = (char*)d_ws;
  unsigned short* xT  = (unsigned short*)(ws);                 //  6,422,528 B
  unsigned short* wpk = (unsigned short*)(ws + 6422528);       //    589,824 B
  float* am_part      = (float*)(ws + 7012352);                //  6,422,528 B
  float* pmax         = (float*)(ws + 13434880);               //  7,340,032 B
  float* part6        = (float*)(ws + 20774912);               //    262,144 B
  float* hbuf         = (float*)(ws + 21037056);               //     32,768 B

  hipLaunchKernelGGL(k_xpose,   dim3(968),  dim3(256), 0, stream, x, cw, xT, wpk);
  hipLaunchKernelGGL(k_conv,    dim3(448),  dim3(128), 0, stream, xT, wpk, cb, am_part);
  hipLaunchKernelGGL(k_pool,    dim3(448),  dim3(256), 0, stream, x, am_part, pmax);
  hipLaunchKernelGGL(k_combine, dim3(256),  dim3(256), 0, stream, pmax, xpool);
  hipLaunchKernelGGL(k_fc6,     dim3(1024), dim3(256), 0, stream, xpool, w6, part6);
  hipLaunchKernelGGL(k_h,       dim3(32),   dim3(256), 0, stream, part6, b6, hbuf);
  hipLaunchKernelGGL(k_fc7,     dim3(256),  dim3(256), 0, stream, hbuf, w7, b7, out);
}